// Round 9
// baseline (7745.016 us; speedup 1.0000x reference)
//
#include <hip/hip_runtime.h>
#include <hip/hip_bf16.h>

// SparseBottleneck v6: hybrid two-wall kernel.
// Rounds 0-7 model: two independent walls -- random-gather loads cap at ~10
// outstanding misses/CU (~10G lines/s device-wide); global atomic-adds are
// fire-and-forget and sustain ~305G ops/s. Round 0 saturated BOTH at once
// (1134us/conv). v6 splits each conv by output region inside one dispatch:
// tiles [0,TG) output-stationary gather path (v3 structure, LDS accum, plain
// stores); rows >= TG*128 input-stationary scatter path (A staged coalesced
// per input tile -> zero gather; atomic scatter). Both paths dedup'd.

typedef __attribute__((ext_vector_type(8))) short short8;
typedef __attribute__((ext_vector_type(4))) float f32x4;

#define CDIM 128
#define BM   128
#define KTAPS 27
#define GLST  65            // G-path lacc stride (odd -> banks spread)
#define SLST  136           // S-path A-tile stride (272B = 17*16B: aligned + ~2-way banks)
#define NEG_SLOPE 0.2f

__device__ __forceinline__ unsigned short f2bf(float x) {
    union { float f; unsigned u; } un; un.f = x;
    unsigned r = un.u + 0x7fffu + ((un.u >> 16) & 1u);   // RNE
    return (unsigned short)(r >> 16);
}

__device__ __forceinline__ float lrelu(float x) {
    return x >= 0.f ? x : NEG_SLOPE * x;
}

__device__ __forceinline__ int swz(int r, int c) {
    return (r << 7) + ((((c >> 3) ^ (r & 15)) << 3));
}

// ---------------------------------------------------------------- converters
__global__ void cvt_feats_kernel(const float* __restrict__ in,
                                 unsigned short* __restrict__ out, int n4) {
    int i = blockIdx.x * blockDim.x + threadIdx.x;
    if (i >= n4) return;
    float4 v = reinterpret_cast<const float4*>(in)[i];
    ushort4 o;
    o.x = f2bf(v.x); o.y = f2bf(v.y); o.z = f2bf(v.z); o.w = f2bf(v.w);
    reinterpret_cast<ushort4*>(out)[i] = o;
}

// W1/W3: [K][Cin][Cout] -> Wt[K][Cout][Cin] bf16. W2 -> W2t[Cout][Cin].
__global__ void cvt_weights_kernel(const float* __restrict__ W1,
                                   const float* __restrict__ W2,
                                   const float* __restrict__ W3,
                                   unsigned short* __restrict__ W1t,
                                   unsigned short* __restrict__ W2t,
                                   unsigned short* __restrict__ W3t) {
    const int KW = KTAPS * 128 * 128;                 // 442368
    int t = blockIdx.x * blockDim.x + threadIdx.x;
    if (t < KW) {
        int k = t >> 14, r = t & 16383, n = r >> 7, kk = r & 127;
        W1t[t] = f2bf(W1[(k << 14) + (kk << 7) + n]);
    } else if (t < 2 * KW) {
        int t2 = t - KW;
        int k = t2 >> 14, r = t2 & 16383, n = r >> 7, kk = r & 127;
        W3t[t2] = f2bf(W3[(k << 14) + (kk << 7) + n]);
    } else if (t < 2 * KW + 16384) {
        int t2 = t - 2 * KW;
        int n = t2 >> 7, kk = t2 & 127;
        W2t[t2] = f2bf(W2[(kk << 7) + n]);
    }
}

// ---------------------------------------------------------------- binning prep
// G path: entries with orow <  split, bin = (orow>>7)*27 + k  (NBg = TG*27)
// S path: entries with orow >= split, bin = (irow>>7)*27 + k  (NB2 = NT*27)
__global__ void hist_g_kernel(const int* __restrict__ out_map,
                              int* __restrict__ cnt, int M, int split) {
    int m = blockIdx.x * 256 + threadIdx.x;
    if (m >= M) return;
    int k = blockIdx.y;
    int orow = out_map[(size_t)k * M + m];
    if (orow < split) atomicAdd(cnt + ((orow >> 7) * KTAPS + k), 1);
}

__global__ void hist_s_kernel(const int* __restrict__ in_map,
                              const int* __restrict__ out_map,
                              int* __restrict__ cnt, int M, int split) {
    int m = blockIdx.x * 256 + threadIdx.x;
    if (m >= M) return;
    int k = blockIdx.y;
    size_t e = (size_t)k * M + m;
    if (out_map[e] >= split) atomicAdd(cnt + ((in_map[e] >> 7) * KTAPS + k), 1);
}

__global__ void scan_a_kernel(const int* __restrict__ cnt, int* __restrict__ cs,
                              int* __restrict__ partials, int NB) {
    __shared__ int sd[256];
    int tid = threadIdx.x, bin = blockIdx.x * 256 + tid;
    int v = (bin < NB) ? ((cnt[bin] + 15) >> 4) : 0;
    sd[tid] = v; __syncthreads();
    for (int off = 1; off < 256; off <<= 1) {
        int t = (tid >= off) ? sd[tid - off] : 0; __syncthreads();
        sd[tid] += t; __syncthreads();
    }
    if (bin < NB) cs[bin] = sd[tid] - v;
    if (tid == 255) partials[blockIdx.x] = sd[255];
}

__global__ void scan_b_kernel(int* __restrict__ partials, int NBb) {
    __shared__ int sd[256];
    int tid = threadIdx.x;
    int v = (tid < NBb) ? partials[tid] : 0;
    sd[tid] = v; __syncthreads();
    for (int off = 1; off < 256; off <<= 1) {
        int t = (tid >= off) ? sd[tid - off] : 0; __syncthreads();
        sd[tid] += t; __syncthreads();
    }
    partials[tid] = sd[tid] - v;
}

__global__ void scan_c_kernel(int* __restrict__ cs, const int* __restrict__ partials,
                              int NB, int NBb) {
    int bin = blockIdx.x * 256 + threadIdx.x;
    if (bin < NB) cs[bin] += partials[blockIdx.x];
    if (bin == 0) cs[NB] = partials[NBb];
}

__global__ void fill_kernel(int* __restrict__ p, int n, int v) {
    int i = blockIdx.x * 256 + threadIdx.x;
    if (i < n) p[i] = v;
}

// G entry: (k<<26) | (irow<<8) | (orow&127);  dummy irow=N (zero row), srow=0
__global__ void scatter_g_kernel(const int* __restrict__ in_map,
                                 const int* __restrict__ out_map,
                                 const int* __restrict__ cs,
                                 int* __restrict__ cursor,
                                 int* __restrict__ pairs, int M, int split) {
    int m = blockIdx.x * 256 + threadIdx.x;
    if (m >= M) return;
    int k = blockIdx.y;
    size_t e = (size_t)k * M + m;
    int orow = out_map[e];
    if (orow >= split) return;
    int irow = in_map[e];
    int bin = (orow >> 7) * KTAPS + k;
    int pos = atomicAdd(cursor + bin, 1);
    pairs[(size_t)cs[bin] * 16 + pos] = (k << 26) | (irow << 8) | (orow & 127);
}

// S entry: (orow<<7) | (irow&127);  sentinel orow=0x3FFFF (>=N -> skip atomics)
__global__ void scatter_s_kernel(const int* __restrict__ in_map,
                                 const int* __restrict__ out_map,
                                 const int* __restrict__ cs,
                                 int* __restrict__ cursor,
                                 int* __restrict__ pairs, int M, int split) {
    int m = blockIdx.x * 256 + threadIdx.x;
    if (m >= M) return;
    int k = blockIdx.y;
    size_t e = (size_t)k * M + m;
    int orow = out_map[e];
    if (orow < split) return;
    int irow = in_map[e];
    int bin = (irow >> 7) * KTAPS + k;
    int pos = atomicAdd(cursor + bin, 1);
    pairs[(size_t)cs[bin] * 16 + pos] = (orow << 7) | (irow & 127);
}

// ---------------------------------------------------------------- hybrid conv
#define ISSUE_A(d0, d1, d2, d3, pkv)                                        \
    {   int irow_ = ((pkv) >> 8) & 0x3FFFF;                                 \
        const unsigned short* ar_ = A + ((size_t)irow_ << 7) + quad * 8;    \
        d0 = *reinterpret_cast<const short8*>(ar_);                         \
        d1 = *reinterpret_cast<const short8*>(ar_ + 32);                    \
        d2 = *reinterpret_cast<const short8*>(ar_ + 64);                    \
        d3 = *reinterpret_cast<const short8*>(ar_ + 96); }

#define LOADW(B, H)                                                         \
    {   const unsigned short* wb_ = Wt + ((size_t)(B) << 14)                \
                  + ((((H) << 6) + lrow) << 7) + quad * 8;                  \
        _Pragma("unroll")                                                   \
        for (int j_ = 0; j_ < 4; ++j_)                                      \
            _Pragma("unroll")                                               \
            for (int s_ = 0; s_ < 4; ++s_)                                  \
                wf[j_][s_] = *reinterpret_cast<const short8*>(wb_ + j_ * 2048 + s_ * 32); }

#define COMPUTE_G(aa0, aa1, aa2, aa3, pkv)                                  \
    {   int srow_ = (pkv) & 127;                                            \
        int ad0_ = srow_ * GLST + quad * 4;                                 \
        _Pragma("unroll")                                                   \
        for (int j_ = 0; j_ < 4; ++j_) {                                    \
            f32x4 acc_ = {0.f, 0.f, 0.f, 0.f};                              \
            acc_ = __builtin_amdgcn_mfma_f32_16x16x32_bf16(wf[j_][0], aa0, acc_, 0, 0, 0); \
            acc_ = __builtin_amdgcn_mfma_f32_16x16x32_bf16(wf[j_][1], aa1, acc_, 0, 0, 0); \
            acc_ = __builtin_amdgcn_mfma_f32_16x16x32_bf16(wf[j_][2], aa2, acc_, 0, 0, 0); \
            acc_ = __builtin_amdgcn_mfma_f32_16x16x32_bf16(wf[j_][3], aa3, acc_, 0, 0, 0); \
            _Pragma("unroll")                                               \
            for (int r_ = 0; r_ < 4; ++r_)                                  \
                __hip_atomic_fetch_add(&lacc[ad0_ + j_ * 16 + r_], acc_[r_],\
                    __ATOMIC_RELAXED, __HIP_MEMORY_SCOPE_WORKGROUP); } }

#define BINCROSS_G(c)                                                       \
    if ((c) >= nextb) {                                                     \
        do { ++bin; nextb = lcsu[bin + 1]; } while ((c) >= nextb);          \
        LOADW(bin, hhalf);                                                  \
    }

template<int MODE>
__global__ __launch_bounds__(512, 4)
void conv_hybrid_kernel(const unsigned short* __restrict__ A,   // [N+1,128] bf16, row N = 0
                        const unsigned short* __restrict__ Wt,  // [27][128][128] bf16
                        const int* __restrict__ pairsg,
                        const int* __restrict__ csg,            // [NBg+1]
                        const int* __restrict__ pairss,
                        const int* __restrict__ css,            // [NB2+1]
                        float* __restrict__ out,                // [N,128] fp32
                        const float* __restrict__ mask,
                        int N, int TG) {
    __shared__ __align__(16) char u[34816 + 128];
    const int tid  = threadIdx.x;
    const int bid  = blockIdx.x;
    const int wid  = tid >> 6, lane = tid & 63;
    const int lrow = lane & 15, quad = lane >> 4;
    int* lcsu = reinterpret_cast<int*>(u + 34816);

    if (bid < 2 * TG) {
        // ================= G path: output-stationary gather (v3 structure)
        float* lacc = reinterpret_cast<float*>(u);              // [128][GLST]
        const int tile  = bid >> 1;
        const int hhalf = bid & 1;

        for (int i = tid; i < 128 * GLST; i += 512) lacc[i] = 0.f;
        if (tid <= KTAPS) lcsu[tid] = csg[tile * KTAPS + tid];
        __syncthreads();

        const int lo = lcsu[0], hi = lcsu[KTAPS];
        const int per = (hi - lo + 7) >> 3;
        int c0 = lo + wid * per;
        int c1 = (c0 + per < hi) ? (c0 + per) : hi;

        if (c0 < c1) {
            int bin = 0;
            while (lcsu[bin + 1] <= c0) ++bin;
            int nextb = lcsu[bin + 1];
            short8 wf[4][4];
            LOADW(bin, hhalf);

            const int cl = c1 - 1;
            int pvc = pairsg[(size_t)c0 * 16 + lrow];
            int pvn = pairsg[(size_t)((c0 + 1 < cl) ? c0 + 1 : cl) * 16 + lrow];
            int pf  = pairsg[(size_t)((c0 + 2 < cl) ? c0 + 2 : cl) * 16 + lrow];
            short8 xa0, xa1, xa2, xa3, ya0, ya1, ya2, ya3;
            ISSUE_A(xa0, xa1, xa2, xa3, pvc);

            int c = c0;
            while (true) {
                {   // body X
                    int pv2 = pf;
                    int i3 = (c + 3 < cl) ? c + 3 : cl;
                    pf = pairsg[(size_t)i3 * 16 + lrow];
                    ISSUE_A(ya0, ya1, ya2, ya3, pvn);
                    __builtin_amdgcn_sched_barrier(0);
                    BINCROSS_G(c);
                    COMPUTE_G(xa0, xa1, xa2, xa3, pvc);
                    pvc = pvn; pvn = pv2;
                }
                if (++c >= c1) break;
                {   // body Y
                    int pv2 = pf;
                    int i3 = (c + 3 < cl) ? c + 3 : cl;
                    pf = pairsg[(size_t)i3 * 16 + lrow];
                    ISSUE_A(xa0, xa1, xa2, xa3, pvn);
                    __builtin_amdgcn_sched_barrier(0);
                    BINCROSS_G(c);
                    COMPUTE_G(ya0, ya1, ya2, ya3, pvc);
                    pvc = pvn; pvn = pv2;
                }
                if (++c >= c1) break;
            }
        }
        __syncthreads();

        // epilogue: plain fp32 stores (MODE1 fuses mask); rows < TG*128 <= N
        const int gbase = tile << 7;
        for (int i = tid; i < 128 * 32; i += 512) {
            int r = i >> 5, cp = i & 31;
            int g = gbase + r;
            float2 o = { lacc[r * GLST + cp * 2], lacc[r * GLST + cp * 2 + 1] };
            if (MODE == 1) { float mv = mask[g]; o.x *= mv; o.y *= mv; }
            *reinterpret_cast<float2*>(out + (size_t)g * CDIM + (hhalf << 6) + cp * 2) = o;
        }
    } else {
        // ================= S path: input-stationary atomic scatter
        unsigned short* tA = reinterpret_cast<unsigned short*>(u); // [128][SLST]
        const int it = bid - 2 * TG;

        for (int cc = tid; cc < 128 * 16; cc += 512) {          // 16B chunks
            int r = cc >> 4, c8 = cc & 15;
            int grow = it * 128 + r;
            short8 v = {0, 0, 0, 0, 0, 0, 0, 0};
            if (grow < N)
                v = *reinterpret_cast<const short8*>(A + (size_t)grow * CDIM + c8 * 8);
            *reinterpret_cast<short8*>(tA + r * SLST + c8 * 8) = v;
        }
        if (tid <= KTAPS) lcsu[tid] = css[it * KTAPS + tid];
        __syncthreads();

        const int lo = lcsu[0], nc = lcsu[KTAPS] - lo;
        const int ntask = nc * 2;                                // (chunk, col-half)
        const int per = (ntask + 7) >> 3;
        int t0 = wid * per;
        int t1 = (t0 + per < ntask) ? (t0 + per) : ntask;

        if (t0 < t1) {
            int h0 = (t0 >= nc) ? 1 : 0;
            int cA = lo + (h0 ? t0 - nc : t0);
            int bin = 0;
            while (lcsu[bin + 1] <= cA) ++bin;
            int nextb = lcsu[bin + 1];
            short8 wf[4][4];
            LOADW(bin, h0);
            int curh = h0;
            int pk = pairss[(size_t)cA * 16 + lrow];

            for (int t = t0; t < t1; ++t) {
                int h = (t >= nc) ? 1 : 0;
                int c = lo + (h ? t - nc : t);
                if (h != curh) {
                    curh = h; bin = 0;
                    while (lcsu[bin + 1] <= c) ++bin;
                    nextb = lcsu[bin + 1];
                    LOADW(bin, h);
                } else if (c >= nextb) {
                    do { ++bin; nextb = lcsu[bin + 1]; } while (c >= nextb);
                    LOADW(bin, h);
                }
                int pkc = pk;
                if (t + 1 < t1) {                                // prefetch next
                    int hn = (t + 1 >= nc) ? 1 : 0;
                    int cn = lo + (hn ? t + 1 - nc : t + 1);
                    pk = pairss[(size_t)cn * 16 + lrow];
                }
                int orow = (pkc >> 7) & 0x3FFFF;
                int irl  = pkc & 127;
                const unsigned short* ar = tA + irl * SLST + quad * 8;
                short8 a0 = *reinterpret_cast<const short8*>(ar);
                short8 a1 = *reinterpret_cast<const short8*>(ar + 32);
                short8 a2 = *reinterpret_cast<const short8*>(ar + 64);
                short8 a3 = *reinterpret_cast<const short8*>(ar + 96);
                bool live = (orow < N);                          // sentinel skip
                float* dst = out + (size_t)orow * CDIM + h * 64 + quad * 4;
                #pragma unroll
                for (int j = 0; j < 4; ++j) {
                    f32x4 acc = {0.f, 0.f, 0.f, 0.f};
                    acc = __builtin_amdgcn_mfma_f32_16x16x32_bf16(wf[j][0], a0, acc, 0, 0, 0);
                    acc = __builtin_amdgcn_mfma_f32_16x16x32_bf16(wf[j][1], a1, acc, 0, 0, 0);
                    acc = __builtin_amdgcn_mfma_f32_16x16x32_bf16(wf[j][2], a2, acc, 0, 0, 0);
                    acc = __builtin_amdgcn_mfma_f32_16x16x32_bf16(wf[j][3], a3, acc, 0, 0, 0);
                    if (live) {
                        #pragma unroll
                        for (int r = 0; r < 4; ++r)
                            unsafeAtomicAdd(dst + j * 16 + r, acc[r]);
                    }
                }
            }
        }
    }
}

// ---------------------------------------------------------------- dense conv2
// c2 = bf16(lrelu( lrelu(c1) @ W2 )) -- reads RAW fp32 c1, fuses both lrelus
__global__ __launch_bounds__(256, 2)
void conv2_kernel(const float* __restrict__ c1,
                  const unsigned short* __restrict__ W2t,
                  unsigned short* __restrict__ c2,
                  int N) {
    const int mbase = blockIdx.x * BM;
    const int tid   = threadIdx.x;

    __shared__ unsigned short lA[BM * CDIM];
    __shared__ unsigned short lW[CDIM * CDIM];

    #pragma unroll
    for (int i = 0; i < 8; ++i) {
        int flat = (i * 256 + tid) * 8;
        int row = flat >> 7, col = flat & 127;
        short8 v = *reinterpret_cast<const short8*>(W2t + flat);
        *reinterpret_cast<short8*>(&lW[swz(row, col)]) = v;
    }

    #pragma unroll
    for (int p = 0; p < 8; ++p) {
        int r = p * 16 + (tid >> 4);
        int c = (tid & 15) * 8;
        int m = mbase + r;
        unsigned short vv[8];
        if (m < N) {
            const float4* src = reinterpret_cast<const float4*>(c1 + (size_t)m * CDIM + c);
            float4 x0 = src[0], x1 = src[1];
            vv[0] = f2bf(lrelu(x0.x)); vv[1] = f2bf(lrelu(x0.y));
            vv[2] = f2bf(lrelu(x0.z)); vv[3] = f2bf(lrelu(x0.w));
            vv[4] = f2bf(lrelu(x1.x)); vv[5] = f2bf(lrelu(x1.y));
            vv[6] = f2bf(lrelu(x1.z)); vv[7] = f2bf(lrelu(x1.w));
        } else {
            #pragma unroll
            for (int q = 0; q < 8; ++q) vv[q] = 0;
        }
        short8 v;
        #pragma unroll
        for (int q = 0; q < 8; ++q) v[q] = (short)vv[q];
        *reinterpret_cast<short8*>(&lA[swz(r, c)]) = v;
    }
    __syncthreads();

    const int wid  = tid >> 6, lane = tid & 63;
    const int wr   = (wid >> 1) * 64, wc = (wid & 1) * 64;
    const int lrow = lane & 15, quad = lane >> 4;

    f32x4 acc[4][4];
    #pragma unroll
    for (int i = 0; i < 4; ++i)
        #pragma unroll
        for (int j = 0; j < 4; ++j)
            acc[i][j] = {0.f, 0.f, 0.f, 0.f};

    #pragma unroll
    for (int s = 0; s < 4; ++s) {
        const int kf = s * 32 + quad * 8;
        short8 a[4], b[4];
        #pragma unroll
        for (int i = 0; i < 4; ++i)
            a[i] = *reinterpret_cast<const short8*>(&lA[swz(wr + i * 16 + lrow, kf)]);
        #pragma unroll
        for (int j = 0; j < 4; ++j)
            b[j] = *reinterpret_cast<const short8*>(&lW[swz(wc + j * 16 + lrow, kf)]);
        #pragma unroll
        for (int i = 0; i < 4; ++i)
            #pragma unroll
            for (int j = 0; j < 4; ++j)
                acc[i][j] = __builtin_amdgcn_mfma_f32_16x16x32_bf16(a[i], b[j], acc[i][j], 0, 0, 0);
    }

    #pragma unroll
    for (int i = 0; i < 4; ++i) {
        #pragma unroll
        for (int reg = 0; reg < 4; ++reg) {
            int m = mbase + wr + i * 16 + quad * 4 + reg;
            if (m < N) {
                unsigned short* dst = c2 + (size_t)m * CDIM + wc + lrow;
                #pragma unroll
                for (int j = 0; j < 4; ++j)
                    dst[j * 16] = f2bf(lrelu(acc[i][j][reg]));
            }
        }
    }
}

// ---------------------------------------------------------------- mask tail
// rows [split, N): out *= mask (S-region of conv3)
__global__ void mask_tail_kernel(float* __restrict__ out,
                                 const float* __restrict__ mask,
                                 int split, int N) {
    int i = blockIdx.x * 256 + threadIdx.x;
    int n4 = (N - split) * 32;
    if (i >= n4) return;
    int row = split + (i >> 5);
    float m = mask[row];
    float4* p = reinterpret_cast<float4*>(out + (size_t)split * CDIM);
    float4 v = p[i];
    v.x *= m; v.y *= m; v.z *= m; v.w *= m;
    p[i] = v;
}

// ---------------------------------------------------------------- launch
extern "C" void kernel_launch(void* const* d_in, const int* in_sizes, int n_in,
                              void* d_out, int out_size, void* d_ws, size_t ws_size,
                              hipStream_t stream) {
    const float* feats   = (const float*)d_in[0];
    const float* W1      = (const float*)d_in[1];
    const float* W2      = (const float*)d_in[2];
    const float* W3      = (const float*)d_in[3];
    const int*   in_map  = (const int*)d_in[4];
    const int*   out_map = (const int*)d_in[5];
    const float* mask    = (const float*)d_in[6];
    float*       out     = (float*)d_out;

    const int K    = KTAPS;
    const int N    = in_sizes[0] / CDIM;          // 200000
    const int M    = in_sizes[4] / K;             // 100000
    const int NT   = (N + 127) >> 7;              // 1563 tiles
    const int TG   = (NT * 35 + 99) / 100;        // gather-path tiles (f = 0.35)
    const int SPL  = TG * 128;                    // output-row split
    const int NBg  = TG * K;                      // G bins
    const int NB2  = NT * K;                      // S bins
    const int NBgb = (NBg + 255) >> 8;
    const int NB2b = (NB2 + 255) >> 8;
    const int CAPg = K * M + 16 * NBg + 16;
    const int CAPs = K * M + 16 * NB2 + 16;

    char* w = (char*)d_ws;
    size_t o = 0;
    auto alloc = [&](size_t bytes) -> void* {
        void* p = w + o; o = (o + bytes + 511) & ~(size_t)511; return p;
    };
    unsigned short* Abf   = (unsigned short*)alloc((size_t)(N + 1) * CDIM * 2);
    unsigned short* W1t   = (unsigned short*)alloc((size_t)K * CDIM * CDIM * 2);
    unsigned short* W3t   = (unsigned short*)alloc((size_t)K * CDIM * CDIM * 2);
    unsigned short* W2t   = (unsigned short*)alloc((size_t)CDIM * CDIM * 2);
    int* cntg     = (int*)alloc((size_t)NBg * 4);
    int* curg     = (int*)alloc((size_t)NBg * 4);
    int* csg      = (int*)alloc((size_t)(NBg + 1) * 4);
    int* cnts     = (int*)alloc((size_t)NB2 * 4);
    int* curs     = (int*)alloc((size_t)NB2 * 4);
    int* css      = (int*)alloc((size_t)(NB2 + 1) * 4);
    int* partials = (int*)alloc(257 * 4);
    int* pairsg   = (int*)alloc((size_t)CAPg * 4);
    int* pairss   = (int*)alloc((size_t)CAPs * 4);
    if (o > ws_size) return;   // fail loudly rather than corrupt

    // convert inputs
    const int n4 = N * CDIM / 4;
    cvt_feats_kernel<<<(n4 + 255) / 256, 256, 0, stream>>>(feats, Abf, n4);
    hipMemsetAsync(Abf + (size_t)N * CDIM, 0, CDIM * 2, stream);  // zero row N
    const int wtot = 2 * K * CDIM * CDIM + CDIM * CDIM;
    cvt_weights_kernel<<<(wtot + 255) / 256, 256, 0, stream>>>(W1, W2, W3, W1t, W2t, W3t);

    // binning (shared by conv1 & conv3)
    hipMemsetAsync(cntg, 0, (size_t)NBg * 4, stream);
    hipMemsetAsync(curg, 0, (size_t)NBg * 4, stream);
    hipMemsetAsync(cnts, 0, (size_t)NB2 * 4, stream);
    hipMemsetAsync(curs, 0, (size_t)NB2 * 4, stream);
    dim3 gmap((M + 255) / 256, K);
    hist_g_kernel<<<gmap, 256, 0, stream>>>(out_map, cntg, M, SPL);
    hist_s_kernel<<<gmap, 256, 0, stream>>>(in_map, out_map, cnts, M, SPL);
    scan_a_kernel<<<NBgb, 256, 0, stream>>>(cntg, csg, partials, NBg);
    scan_b_kernel<<<1, 256, 0, stream>>>(partials, NBgb);
    scan_c_kernel<<<NBgb, 256, 0, stream>>>(csg, partials, NBg, NBgb);
    scan_a_kernel<<<NB2b, 256, 0, stream>>>(cnts, css, partials, NB2);
    scan_b_kernel<<<1, 256, 0, stream>>>(partials, NB2b);
    scan_c_kernel<<<NB2b, 256, 0, stream>>>(css, partials, NB2, NB2b);
    const int DUMG = (N << 8);                       // irow=N (zero row), srow=0
    const int SENT = (0x3FFFF << 7);                 // orow sentinel, irl=0
    fill_kernel<<<(CAPg + 255) / 256, 256, 0, stream>>>(pairsg, CAPg, DUMG);
    fill_kernel<<<(CAPs + 255) / 256, 256, 0, stream>>>(pairss, CAPs, SENT);
    scatter_g_kernel<<<gmap, 256, 0, stream>>>(in_map, out_map, csg, curg, pairsg, M, SPL);
    scatter_s_kernel<<<gmap, 256, 0, stream>>>(in_map, out_map, css, curs, pairss, M, SPL);

    const int grid = 2 * TG + NT;

    // conv1: raw fp32 sums into out (G stores / S atomics); conv2 applies lrelu
    hipMemsetAsync(out + (size_t)SPL * CDIM, 0, (size_t)(N - SPL) * CDIM * 4, stream);
    conv_hybrid_kernel<0><<<grid, 512, 0, stream>>>(Abf, W1t, pairsg, csg, pairss, css,
                                                    out, mask, N, TG);
    // conv2: c2 = bf16(lrelu(lrelu(c1) @ W2)) -> Abf (row N stays zero)
    conv2_kernel<<<NT, 256, 0, stream>>>(out, W2t, Abf, N);
    // conv3: G fuses mask; S raw + tail mask
    hipMemsetAsync(out + (size_t)SPL * CDIM, 0, (size_t)(N - SPL) * CDIM * 4, stream);
    conv_hybrid_kernel<1><<<grid, 512, 0, stream>>>(Abf, W3t, pairsg, csg, pairss, css,
                                                    out, mask, N, TG);
    mask_tail_kernel<<<((N - SPL) * 32 + 255) / 256, 256, 0, stream>>>(out, mask, SPL, N);
}